// Round 1
// baseline (251.318 us; speedup 1.0000x reference)
//
#include <hip/hip_runtime.h>
#include <cstdint>

#define LDP 136          // padded LDS row stride in bf16 elems (272B, 16B-aligned)
#define INFV 3.0e38f

typedef short bf16x8 __attribute__((ext_vector_type(8)));
typedef float f32x4  __attribute__((ext_vector_type(4)));

__device__ inline float bf2f(uint32_t bits){
  return __builtin_bit_cast(float, bits << 16);
}
__device__ inline ushort f2bf(float f){
  uint32_t u = __builtin_bit_cast(uint32_t, f);
  u += 0x7fffu + ((u >> 16) & 1u);   // round-to-nearest-even
  return (ushort)(u >> 16);
}

// ---------------------------------------------------------------------------
// Kernel 1: cost[b][i][j] = ||s1[b,i]||^2 + ||s2[b,j]||^2 - 2*dot  (bf16 out)
// One block per (tile, batch): 128x128 output tile, K=128, bf16 MFMA.
// ---------------------------------------------------------------------------
__global__ __launch_bounds__(256) void dtw_cost_gemm(
    const float* __restrict__ s1, const float* __restrict__ s2,
    ushort* __restrict__ cost)
{
  __shared__ ushort As[128*LDP];
  __shared__ ushort Bs[128*LDP];
  __shared__ float  n1s[128];
  __shared__ float  n2s[128];

  const int b  = blockIdx.y;
  const int ti = blockIdx.x / 3;
  const int tj = blockIdx.x % 3;
  const int t  = threadIdx.x;

  // ---- stage A,B tiles fp32 -> bf16 into LDS ----
  {
    const int row = t >> 1;
    const int par = t & 1;
    const float* Arow = s1 + ((size_t)(b*384 + ti*128 + row)) * 128;
    const float* Brow = s2 + ((size_t)(b*384 + tj*128 + row)) * 128;
    ushort* Asr = As + row*LDP;
    ushort* Bsr = Bs + row*LDP;
#pragma unroll
    for (int q = 0; q < 16; q++){
      // bank-derotated quad order: keeps ds_write_b64 at the bandwidth floor
      const int col = ((2*q + par + 15*row) & 31) * 4;
      float4 va = *(const float4*)(Arow + col);
      float4 vb = *(const float4*)(Brow + col);
      ushort4 ua = make_ushort4(f2bf(va.x), f2bf(va.y), f2bf(va.z), f2bf(va.w));
      ushort4 ub = make_ushort4(f2bf(vb.x), f2bf(vb.y), f2bf(vb.z), f2bf(vb.w));
      *(ushort4*)(Asr + col) = ua;
      *(ushort4*)(Bsr + col) = ub;
    }
  }
  __syncthreads();

  // ---- row norms from the bf16 tiles (consistent with the bf16 dot) ----
  {
    const ushort* rowp = (t < 128) ? (As + t*LDP) : (Bs + (t-128)*LDP);
    float s = 0.0f;
#pragma unroll
    for (int e = 0; e < 128; e += 8){
      bf16x8 v = *(const bf16x8*)(rowp + e);
#pragma unroll
      for (int k = 0; k < 8; k++){
        float f = bf2f((uint16_t)v[k]);
        s += f*f;
      }
    }
    if (t < 128) n1s[t] = s; else n2s[t-128] = s;
  }
  __syncthreads();

  // ---- MFMA: 4 waves in 2x2, each 64x64 via 4x4 frags of 16x16x32 ----
  const int lane = t & 63;
  const int wid  = t >> 6;
  const int wr = wid >> 1, wc = wid & 1;
  const int lrow = lane & 15;
  const int lk   = lane >> 4;

  f32x4 acc[4][4] = {};
#pragma unroll
  for (int kk = 0; kk < 4; kk++){
    const int kb = kk*32 + lk*8;
    bf16x8 af[4], bfv[4];
#pragma unroll
    for (int f = 0; f < 4; f++){
      af[f]  = *(const bf16x8*)(As + (wr*64 + f*16 + lrow)*LDP + kb);
      bfv[f] = *(const bf16x8*)(Bs + (wc*64 + f*16 + lrow)*LDP + kb);
    }
#pragma unroll
    for (int i = 0; i < 4; i++)
#pragma unroll
      for (int j = 0; j < 4; j++)
        acc[i][j] = __builtin_amdgcn_mfma_f32_16x16x32_bf16(af[i], bfv[j], acc[i][j], 0, 0, 0);
  }

  // ---- epilogue: cost = n1 + n2 - 2*dot, store bf16 ----
  ushort* Cb = cost + (size_t)b * 147456;  // 384*384
  const int i0 = ti*128 + wr*64;
  const int j0 = tj*128 + wc*64;
  float n2v[4];
#pragma unroll
  for (int fj = 0; fj < 4; fj++) n2v[fj] = n2s[wc*64 + fj*16 + lrow];
#pragma unroll
  for (int fi = 0; fi < 4; fi++){
#pragma unroll
    for (int r = 0; r < 4; r++){
      const int il = wr*64 + fi*16 + lk*4 + r;  // local row
      const int i  = i0 + fi*16 + lk*4 + r;     // global row
      const float n1v = n1s[il];
#pragma unroll
      for (int fj = 0; fj < 4; fj++){
        float cv = n1v + n2v[fj] - 2.0f*acc[fi][fj][r];
        Cb[(size_t)i*384 + (j0 + fj*16 + lrow)] = f2bf(cv);
      }
    }
  }
}

// ---------------------------------------------------------------------------
// Kernel 2: DTW DP. One wave per batch; 64 lanes x 6 cols = 384.
// Row recurrence turned into prefix-sum + prefix-min scans (min-plus scan).
// ---------------------------------------------------------------------------
__global__ __launch_bounds__(64) void dtw_dp(
    const ushort* __restrict__ cost, float* __restrict__ partial)
{
  const int b    = blockIdx.x;
  const int lane = threadIdx.x;
  const uint32_t* Cw = (const uint32_t*)(cost + (size_t)b * 147456);
  const int wb = lane * 3;   // 3 dwords = 6 bf16 per lane per row (row = 192 dwords)

  uint32_t w0 = Cw[wb], w1 = Cw[wb+1], w2 = Cw[wb+2];

  float r0,r1,r2,r3,r4,r5;
  // ---- row 0: inclusive prefix sum of cost row 0 ----
  {
    float c0=bf2f(w0&0xffffu), c1=bf2f(w0>>16),
          c2=bf2f(w1&0xffffu), c3=bf2f(w1>>16),
          c4=bf2f(w2&0xffffu), c5=bf2f(w2>>16);
    float s0=c0, s1=s0+c1, s2=s1+c2, s3=s2+c3, s4=s3+c4, s5=s4+c5;
    float incl = s5;
#pragma unroll
    for (int d = 1; d < 64; d <<= 1){
      float tv = __shfl_up(incl, d, 64);
      if (lane >= d) incl += tv;
    }
    float excl = incl - s5;
    r0=s0+excl; r1=s1+excl; r2=s2+excl; r3=s3+excl; r4=s4+excl; r5=s5+excl;
  }

  // preload row 1
  w0 = Cw[192+wb]; w1 = Cw[192+wb+1]; w2 = Cw[192+wb+2];

  for (int i = 1; i < 384; i++){
    float c0=bf2f(w0&0xffffu), c1=bf2f(w0>>16),
          c2=bf2f(w1&0xffffu), c3=bf2f(w1>>16),
          c4=bf2f(w2&0xffffu), c5=bf2f(w2>>16);
    if (i < 383){  // prefetch next row while this row's scans run
      const uint32_t* p = Cw + (size_t)(i+1)*192 + wb;
      w0 = p[0]; w1 = p[1]; w2 = p[2];
    }

    // a[j] = c[j] + min(prev[j], prev[j-1])
    float up  = __shfl_up(r5, 1, 64);
    float pm0 = (lane == 0) ? INFV : up;
    float a0 = c0 + fminf(r0, pm0);
    float a1 = c1 + fminf(r1, r0);
    float a2 = c2 + fminf(r2, r1);
    float a3 = c3 + fminf(r3, r2);
    float a4 = c4 + fminf(r4, r3);
    float a5 = c5 + fminf(r5, r4);

    // S = inclusive prefix sum of c
    float s0=c0, s1=s0+c1, s2=s1+c2, s3=s2+c3, s4=s3+c4, s5=s4+c5;
    float tot = s5, incl = tot;
#pragma unroll
    for (int d = 1; d < 64; d <<= 1){
      float tv = __shfl_up(incl, d, 64);
      if (lane >= d) incl += tv;
    }
    float excl = incl - tot;
    s0+=excl; s1+=excl; s2+=excl; s3+=excl; s4+=excl; s5+=excl;

    // prefix-min of (a - S); row = prefmin + S
    float m0 = a0-s0;
    float m1 = fminf(m0, a1-s1);
    float m2 = fminf(m1, a2-s2);
    float m3 = fminf(m2, a3-s3);
    float m4 = fminf(m3, a4-s4);
    float m5 = fminf(m4, a5-s5);
    float e = __shfl_up(m5, 1, 64);
    e = (lane == 0) ? INFV : e;
#pragma unroll
    for (int d = 1; d < 64; d <<= 1){
      float tv = __shfl_up(e, d, 64);
      if (lane >= d) e = fminf(e, tv);
    }
    r0 = fminf(m0,e)+s0;
    r1 = fminf(m1,e)+s1;
    r2 = fminf(m2,e)+s2;
    r3 = fminf(m3,e)+s3;
    r4 = fminf(m4,e)+s4;
    r5 = fminf(m5,e)+s5;
  }

  if (lane == 63) partial[b] = r5;
}

// ---------------------------------------------------------------------------
// Kernel 3: mean of 128 partials -> out[0]
// ---------------------------------------------------------------------------
__global__ __launch_bounds__(64) void dtw_reduce(
    const float* __restrict__ partial, float* __restrict__ out)
{
  const int l = threadIdx.x;
  float v = partial[l] + partial[l + 64];
#pragma unroll
  for (int d = 32; d >= 1; d >>= 1) v += __shfl_xor(v, d, 64);
  if (l == 0) out[0] = v * (1.0f/128.0f);
}

extern "C" void kernel_launch(void* const* d_in, const int* in_sizes, int n_in,
                              void* d_out, int out_size, void* d_ws, size_t ws_size,
                              hipStream_t stream)
{
  (void)in_sizes; (void)n_in; (void)out_size; (void)ws_size;
  const float* s1 = (const float*)d_in[0];
  const float* s2 = (const float*)d_in[1];
  float* out = (float*)d_out;

  ushort* cost    = (ushort*)d_ws;                                   // 128*384*384*2 B
  float*  partial = (float*)((char*)d_ws + (size_t)128*147456*2);    // 128 floats

  dtw_cost_gemm<<<dim3(9, 128), dim3(256), 0, stream>>>(s1, s2, cost);
  dtw_dp<<<dim3(128), dim3(64), 0, stream>>>(cost, partial);
  dtw_reduce<<<dim3(1), dim3(64), 0, stream>>>(partial, out);
}

// Round 2
// 206.279 us; speedup vs baseline: 1.2183x; 1.2183x over previous
//
#include <hip/hip_runtime.h>
#include <cstdint>

#define LDP 136          // padded LDS row stride in bf16 elems (272B, 16B-aligned)
#define INFV 3.0e38f

typedef short bf16x8 __attribute__((ext_vector_type(8)));
typedef float f32x4  __attribute__((ext_vector_type(4)));

__device__ inline float bf2f(uint32_t bits){
  return __builtin_bit_cast(float, bits << 16);
}
__device__ inline ushort f2bf(float f){
  uint32_t u = __builtin_bit_cast(uint32_t, f);
  u += 0x7fffu + ((u >> 16) & 1u);   // round-to-nearest-even
  return (ushort)(u >> 16);
}

// ---- DPP helpers: VALU cross-lane (no ds_bpermute) ------------------------
// update_dpp(old, src, ctrl, row_mask, bank_mask, bound_ctrl=false):
// invalid source lanes read `old`.
#define DPPF(x, oldv, ctrl) \
  __builtin_bit_cast(float, __builtin_amdgcn_update_dpp( \
      __builtin_bit_cast(int,(oldv)), __builtin_bit_cast(int,(x)), \
      (ctrl), 0xf, 0xf, false))

__device__ inline float scan_add16(float x){   // inclusive add-scan within 16-lane row
  x += DPPF(x, 0.0f, 0x111);
  x += DPPF(x, 0.0f, 0x112);
  x += DPPF(x, 0.0f, 0x114);
  x += DPPF(x, 0.0f, 0x118);
  return x;
}
__device__ inline float scan_min16(float x){   // inclusive min-scan within 16-lane row
  x = fminf(x, DPPF(x, INFV, 0x111));
  x = fminf(x, DPPF(x, INFV, 0x112));
  x = fminf(x, DPPF(x, INFV, 0x114));
  x = fminf(x, DPPF(x, INFV, 0x118));
  return x;
}
__device__ inline float rl(float v, int l){    // readlane (uniform, VALU)
  return __builtin_bit_cast(float, __builtin_amdgcn_readlane(__builtin_bit_cast(int, v), l));
}

// ---------------------------------------------------------------------------
// Kernel 1: cost[b][i][j] = ||s1[b,i]||^2 + ||s2[b,j]||^2 - 2*dot  (bf16 out)
// One block per (tile, batch): 128x128 output tile, K=128, bf16 MFMA.
// ---------------------------------------------------------------------------
__global__ __launch_bounds__(256) void dtw_cost_gemm(
    const float* __restrict__ s1, const float* __restrict__ s2,
    ushort* __restrict__ cost)
{
  __shared__ ushort As[128*LDP];
  __shared__ ushort Bs[128*LDP];
  __shared__ float  n1s[128];
  __shared__ float  n2s[128];

  const int b  = blockIdx.y;
  const int ti = blockIdx.x / 3;
  const int tj = blockIdx.x % 3;
  const int t  = threadIdx.x;

  // ---- stage A,B tiles fp32 -> bf16 into LDS ----
  {
    const int row = t >> 1;
    const int par = t & 1;
    const float* Arow = s1 + ((size_t)(b*384 + ti*128 + row)) * 128;
    const float* Brow = s2 + ((size_t)(b*384 + tj*128 + row)) * 128;
    ushort* Asr = As + row*LDP;
    ushort* Bsr = Bs + row*LDP;
#pragma unroll
    for (int q = 0; q < 16; q++){
      const int col = ((2*q + par + 15*row) & 31) * 4;
      float4 va = *(const float4*)(Arow + col);
      float4 vb = *(const float4*)(Brow + col);
      ushort4 ua = make_ushort4(f2bf(va.x), f2bf(va.y), f2bf(va.z), f2bf(va.w));
      ushort4 ub = make_ushort4(f2bf(vb.x), f2bf(vb.y), f2bf(vb.z), f2bf(vb.w));
      *(ushort4*)(Asr + col) = ua;
      *(ushort4*)(Bsr + col) = ub;
    }
  }
  __syncthreads();

  // ---- row norms from the bf16 tiles (consistent with the bf16 dot) ----
  {
    const ushort* rowp = (t < 128) ? (As + t*LDP) : (Bs + (t-128)*LDP);
    float s = 0.0f;
#pragma unroll
    for (int e = 0; e < 128; e += 8){
      bf16x8 v = *(const bf16x8*)(rowp + e);
#pragma unroll
      for (int k = 0; k < 8; k++){
        float f = bf2f((uint16_t)v[k]);
        s += f*f;
      }
    }
    if (t < 128) n1s[t] = s; else n2s[t-128] = s;
  }
  __syncthreads();

  // ---- MFMA: 4 waves in 2x2, each 64x64 via 4x4 frags of 16x16x32 ----
  const int lane = t & 63;
  const int wid  = t >> 6;
  const int wr = wid >> 1, wc = wid & 1;
  const int lrow = lane & 15;
  const int lk   = lane >> 4;

  f32x4 acc[4][4] = {};
#pragma unroll
  for (int kk = 0; kk < 4; kk++){
    const int kb = kk*32 + lk*8;
    bf16x8 af[4], bfv[4];
#pragma unroll
    for (int f = 0; f < 4; f++){
      af[f]  = *(const bf16x8*)(As + (wr*64 + f*16 + lrow)*LDP + kb);
      bfv[f] = *(const bf16x8*)(Bs + (wc*64 + f*16 + lrow)*LDP + kb);
    }
#pragma unroll
    for (int i = 0; i < 4; i++)
#pragma unroll
      for (int j = 0; j < 4; j++)
        acc[i][j] = __builtin_amdgcn_mfma_f32_16x16x32_bf16(af[i], bfv[j], acc[i][j], 0, 0, 0);
  }

  // ---- epilogue: cost = n1 + n2 - 2*dot, store bf16 ----
  ushort* Cb = cost + (size_t)b * 147456;  // 384*384
  const int i0 = ti*128 + wr*64;
  const int j0 = tj*128 + wc*64;
  float n2v[4];
#pragma unroll
  for (int fj = 0; fj < 4; fj++) n2v[fj] = n2s[wc*64 + fj*16 + lrow];
#pragma unroll
  for (int fi = 0; fi < 4; fi++){
#pragma unroll
    for (int r = 0; r < 4; r++){
      const int il = wr*64 + fi*16 + lk*4 + r;  // local row
      const int i  = i0 + fi*16 + lk*4 + r;     // global row
      const float n1v = n1s[il];
#pragma unroll
      for (int fj = 0; fj < 4; fj++){
        float cv = n1v + n2v[fj] - 2.0f*acc[fi][fj][r];
        Cb[(size_t)i*384 + (j0 + fj*16 + lrow)] = f2bf(cv);
      }
    }
  }
}

// ---------------------------------------------------------------------------
// Kernel 2: DTW DP. One wave per batch; 64 lanes x 6 cols = 384.
// Row recurrence = prefix-sum + prefix-min (min-plus) scans, implemented with
// DPP row_shr (VALU) + readlane row-boundary fixups. Zero ds ops in the loop.
// ---------------------------------------------------------------------------
__global__ __launch_bounds__(64) void dtw_dp(
    const ushort* __restrict__ cost, float* __restrict__ partial)
{
  const int b    = blockIdx.x;
  const int lane = threadIdx.x;
  const int row  = lane >> 4;           // 16-lane DPP row id (0..3)
  const bool l16z = (lane & 15) == 0;   // first lane of a DPP row
  const uint32_t* Cw = (const uint32_t*)(cost + (size_t)b * 147456);
  const int wb = lane * 3;   // 3 dwords = 6 bf16 per lane per row (row = 192 dwords)

  float r0,r1,r2,r3,r4,r5;
  // ---- row 0: inclusive prefix sum of cost row 0 ----
  {
    uint32_t w0 = Cw[wb], w1 = Cw[wb+1], w2 = Cw[wb+2];
    float c0=bf2f(w0&0xffffu), c1=bf2f(w0>>16),
          c2=bf2f(w1&0xffffu), c3=bf2f(w1>>16),
          c4=bf2f(w2&0xffffu), c5=bf2f(w2>>16);
    float s0=c0, s1=s0+c1, s2=s1+c2, s3=s2+c3, s4=s3+c4, s5=s4+c5;
    float incl = scan_add16(s5);
    float exl  = DPPF(incl, 0.0f, 0x111);
    float t0 = rl(incl,15), t1 = rl(incl,31), t2 = rl(incl,47);
    float rowoff = (row==0)? 0.0f : (row==1)? t0 : (row==2)? (t0+t1) : (t0+t1+t2);
    float excl = exl + rowoff;
    r0=s0+excl; r1=s1+excl; r2=s2+excl; r3=s3+excl; r4=s4+excl; r5=s5+excl;
  }

#define ROW_BODY(W0, W1, W2) do { \
    float c0=bf2f((W0)&0xffffu), c1=bf2f((W0)>>16), \
          c2=bf2f((W1)&0xffffu), c3=bf2f((W1)>>16), \
          c4=bf2f((W2)&0xffffu), c5=bf2f((W2)>>16); \
    /* prev-row r5 shifted right by one lane */ \
    float yv = DPPF(r5, INFV, 0x111); \
    float q0 = rl(r5,15), q1 = rl(r5,31), q2 = rl(r5,47); \
    float fix = (lane==16)? q0 : (lane==32)? q1 : q2; \
    float pm0 = l16z ? ((lane==0)? INFV : fix) : yv; \
    float a0 = c0 + fminf(r0, pm0); \
    float a1 = c1 + fminf(r1, r0); \
    float a2 = c2 + fminf(r2, r1); \
    float a3 = c3 + fminf(r3, r2); \
    float a4 = c4 + fminf(r4, r3); \
    float a5 = c5 + fminf(r5, r4); \
    /* S = inclusive prefix sum of c across 384 */ \
    float s0=c0, s1=s0+c1, s2=s1+c2, s3=s2+c3, s4=s3+c4, s5=s4+c5; \
    float incl = scan_add16(s5); \
    float exl  = DPPF(incl, 0.0f, 0x111); \
    float t0 = rl(incl,15), t1 = rl(incl,31), t2 = rl(incl,47); \
    float rowoff = (row==0)? 0.0f : (row==1)? t0 : (row==2)? (t0+t1) : (t0+t1+t2); \
    float excl = exl + rowoff; \
    s0+=excl; s1+=excl; s2+=excl; s3+=excl; s4+=excl; s5+=excl; \
    /* prefix-min of (a - S); row = min(m, e) + S */ \
    float m0 = a0-s0; \
    float m1 = fminf(m0, a1-s1); \
    float m2 = fminf(m1, a2-s2); \
    float m3 = fminf(m2, a3-s3); \
    float m4 = fminf(m3, a4-s4); \
    float m5v = fminf(m4, a5-s5); \
    float im = scan_min16(m5v); \
    float ym = DPPF(im, INFV, 0x111); \
    float u0 = rl(im,15), u1 = rl(im,31), u2 = rl(im,47); \
    float moff = (row==0)? INFV : (row==1)? u0 : (row==2)? fminf(u0,u1) : fminf(u0,fminf(u1,u2)); \
    float e = fminf(ym, moff); \
    r0 = fminf(m0,e)+s0; \
    r1 = fminf(m1,e)+s1; \
    r2 = fminf(m2,e)+s2; \
    r3 = fminf(m3,e)+s3; \
    r4 = fminf(m4,e)+s4; \
    r5 = fminf(m5v,e)+s5; \
  } while(0)

  // 8-deep prefetch ring (static indexing via unroll-by-8)
  uint32_t pw[8][3];
#pragma unroll
  for (int u = 0; u < 8; u++){
    const uint32_t* p = Cw + (size_t)(1+u)*192 + wb;
    pw[u][0]=p[0]; pw[u][1]=p[1]; pw[u][2]=p[2];
  }

  for (int base = 1; base < 384; base += 8){
#pragma unroll
    for (int u = 0; u < 8; u++){
      const int i = base + u;
      if (i < 384){
        uint32_t w0 = pw[u][0], w1 = pw[u][1], w2 = pw[u][2];
        if (i + 8 < 384){
          const uint32_t* p = Cw + (size_t)(i+8)*192 + wb;
          pw[u][0]=p[0]; pw[u][1]=p[1]; pw[u][2]=p[2];
        }
        ROW_BODY(w0, w1, w2);
      }
    }
  }

  if (lane == 63) partial[b] = r5;
}

// ---------------------------------------------------------------------------
// Kernel 3: mean of 128 partials -> out[0]
// ---------------------------------------------------------------------------
__global__ __launch_bounds__(64) void dtw_reduce(
    const float* __restrict__ partial, float* __restrict__ out)
{
  const int l = threadIdx.x;
  float v = partial[l] + partial[l + 64];
#pragma unroll
  for (int d = 32; d >= 1; d >>= 1) v += __shfl_xor(v, d, 64);
  if (l == 0) out[0] = v * (1.0f/128.0f);
}

extern "C" void kernel_launch(void* const* d_in, const int* in_sizes, int n_in,
                              void* d_out, int out_size, void* d_ws, size_t ws_size,
                              hipStream_t stream)
{
  (void)in_sizes; (void)n_in; (void)out_size; (void)ws_size;
  const float* s1 = (const float*)d_in[0];
  const float* s2 = (const float*)d_in[1];
  float* out = (float*)d_out;

  ushort* cost    = (ushort*)d_ws;                                   // 128*384*384*2 B
  float*  partial = (float*)((char*)d_ws + (size_t)128*147456*2);    // 128 floats

  dtw_cost_gemm<<<dim3(9, 128), dim3(256), 0, stream>>>(s1, s2, cost);
  dtw_dp<<<dim3(128), dim3(64), 0, stream>>>(cost, partial);
  dtw_reduce<<<dim3(1), dim3(64), 0, stream>>>(partial, out);
}

// Round 3
// 198.160 us; speedup vs baseline: 1.2683x; 1.0410x over previous
//
#include <hip/hip_runtime.h>
#include <cstdint>

#define LDP 136          // padded LDS row stride in bf16 elems (272B, 16B-aligned)
#define INFV 3.0e38f

typedef short bf16x8 __attribute__((ext_vector_type(8)));
typedef float f32x4  __attribute__((ext_vector_type(4)));

__device__ inline float bf2f(uint32_t bits){
  return __builtin_bit_cast(float, bits << 16);
}
__device__ inline ushort f2bf(float f){
  uint32_t u = __builtin_bit_cast(uint32_t, f);
  u += 0x7fffu + ((u >> 16) & 1u);   // round-to-nearest-even
  return (ushort)(u >> 16);
}

// ---- DPP helpers: VALU cross-lane (no ds_bpermute) ------------------------
#define DPPF(x, oldv, ctrl) \
  __builtin_bit_cast(float, __builtin_amdgcn_update_dpp( \
      __builtin_bit_cast(int,(oldv)), __builtin_bit_cast(int,(x)), \
      (ctrl), 0xf, 0xf, false))

__device__ inline float scan_add16(float x){   // inclusive add-scan within 16-lane row
  x += DPPF(x, 0.0f, 0x111);
  x += DPPF(x, 0.0f, 0x112);
  x += DPPF(x, 0.0f, 0x114);
  x += DPPF(x, 0.0f, 0x118);
  return x;
}
__device__ inline float scan_min16(float x){   // inclusive min-scan within 16-lane row
  x = fminf(x, DPPF(x, INFV, 0x111));
  x = fminf(x, DPPF(x, INFV, 0x112));
  x = fminf(x, DPPF(x, INFV, 0x114));
  x = fminf(x, DPPF(x, INFV, 0x118));
  return x;
}
__device__ inline float rl(float v, int l){    // readlane (uniform, VALU)
  return __builtin_bit_cast(float, __builtin_amdgcn_readlane(__builtin_bit_cast(int, v), l));
}

// ---------------------------------------------------------------------------
// Kernel 1: cost[b][i][j] = ||s1[b,i]||^2 + ||s2[b,j]||^2 - 2*dot  (bf16 out)
// ---------------------------------------------------------------------------
__global__ __launch_bounds__(256) void dtw_cost_gemm(
    const float* __restrict__ s1, const float* __restrict__ s2,
    ushort* __restrict__ cost)
{
  __shared__ ushort As[128*LDP];
  __shared__ ushort Bs[128*LDP];
  __shared__ float  n1s[128];
  __shared__ float  n2s[128];

  const int b  = blockIdx.y;
  const int ti = blockIdx.x / 3;
  const int tj = blockIdx.x % 3;
  const int t  = threadIdx.x;

  // ---- stage A,B tiles fp32 -> bf16 into LDS ----
  {
    const int row = t >> 1;
    const int par = t & 1;
    const float* Arow = s1 + ((size_t)(b*384 + ti*128 + row)) * 128;
    const float* Brow = s2 + ((size_t)(b*384 + tj*128 + row)) * 128;
    ushort* Asr = As + row*LDP;
    ushort* Bsr = Bs + row*LDP;
#pragma unroll
    for (int q = 0; q < 16; q++){
      const int col = ((2*q + par + 15*row) & 31) * 4;
      float4 va = *(const float4*)(Arow + col);
      float4 vb = *(const float4*)(Brow + col);
      ushort4 ua = make_ushort4(f2bf(va.x), f2bf(va.y), f2bf(va.z), f2bf(va.w));
      ushort4 ub = make_ushort4(f2bf(vb.x), f2bf(vb.y), f2bf(vb.z), f2bf(vb.w));
      *(ushort4*)(Asr + col) = ua;
      *(ushort4*)(Bsr + col) = ub;
    }
  }
  __syncthreads();

  // ---- row norms from the bf16 tiles ----
  {
    const ushort* rowp = (t < 128) ? (As + t*LDP) : (Bs + (t-128)*LDP);
    float s = 0.0f;
#pragma unroll
    for (int e = 0; e < 128; e += 8){
      bf16x8 v = *(const bf16x8*)(rowp + e);
#pragma unroll
      for (int k = 0; k < 8; k++){
        float f = bf2f((uint16_t)v[k]);
        s += f*f;
      }
    }
    if (t < 128) n1s[t] = s; else n2s[t-128] = s;
  }
  __syncthreads();

  // ---- MFMA: 4 waves in 2x2, each 64x64 via 4x4 frags of 16x16x32 ----
  const int lane = t & 63;
  const int wid  = t >> 6;
  const int wr = wid >> 1, wc = wid & 1;
  const int lrow = lane & 15;
  const int lk   = lane >> 4;

  f32x4 acc[4][4] = {};
#pragma unroll
  for (int kk = 0; kk < 4; kk++){
    const int kb = kk*32 + lk*8;
    bf16x8 af[4], bfv[4];
#pragma unroll
    for (int f = 0; f < 4; f++){
      af[f]  = *(const bf16x8*)(As + (wr*64 + f*16 + lrow)*LDP + kb);
      bfv[f] = *(const bf16x8*)(Bs + (wc*64 + f*16 + lrow)*LDP + kb);
    }
#pragma unroll
    for (int i = 0; i < 4; i++)
#pragma unroll
      for (int j = 0; j < 4; j++)
        acc[i][j] = __builtin_amdgcn_mfma_f32_16x16x32_bf16(af[i], bfv[j], acc[i][j], 0, 0, 0);
  }

  // ---- epilogue ----
  ushort* Cb = cost + (size_t)b * 147456;  // 384*384
  const int i0 = ti*128 + wr*64;
  const int j0 = tj*128 + wc*64;
  float n2v[4];
#pragma unroll
  for (int fj = 0; fj < 4; fj++) n2v[fj] = n2s[wc*64 + fj*16 + lrow];
#pragma unroll
  for (int fi = 0; fi < 4; fi++){
#pragma unroll
    for (int r = 0; r < 4; r++){
      const int il = wr*64 + fi*16 + lk*4 + r;
      const int i  = i0 + fi*16 + lk*4 + r;
      const float n1v = n1s[il];
#pragma unroll
      for (int fj = 0; fj < 4; fj++){
        float cv = n1v + n2v[fj] - 2.0f*acc[fi][fj][r];
        Cb[(size_t)i*384 + (j0 + fj*16 + lrow)] = f2bf(cv);
      }
    }
  }
}

// ---------------------------------------------------------------------------
// Kernel 2: DTW DP. One wave per batch; 64 lanes x 6 cols = 384.
// min-plus scan row recurrence (DPP + readlane), double-buffered 8-row
// register rings so loads are issued a full phase (~1600 cy) before use.
// ---------------------------------------------------------------------------
__global__ __launch_bounds__(64, 1) void dtw_dp(
    const ushort* __restrict__ cost, float* __restrict__ partial)
{
  const int b    = blockIdx.x;
  const int lane = threadIdx.x;
  const int row  = lane >> 4;           // 16-lane DPP row id (0..3)
  const bool l16z = (lane & 15) == 0;
  const uint32_t* Cw = (const uint32_t*)(cost + (size_t)b * 147456);
  const int wb = lane * 3;   // 3 dwords = 6 bf16 per lane per row (row = 192 dwords)

  float r0,r1,r2,r3,r4,r5;

#define LOADR(ring, u, rowidx) do { \
    int rr_ = (rowidx); rr_ = rr_ > 383 ? 383 : rr_; \
    const uint32_t* p_ = Cw + (size_t)rr_*192 + wb; \
    ring[u][0]=p_[0]; ring[u][1]=p_[1]; ring[u][2]=p_[2]; \
  } while(0)

#define ROW_BODY(W0, W1, W2) do { \
    float c0=bf2f((W0)&0xffffu), c1=bf2f((W0)>>16), \
          c2=bf2f((W1)&0xffffu), c3=bf2f((W1)>>16), \
          c4=bf2f((W2)&0xffffu), c5=bf2f((W2)>>16); \
    /* prev-row r5 shifted right by one lane */ \
    float yv = DPPF(r5, INFV, 0x111); \
    float q0 = rl(r5,15), q1 = rl(r5,31), q2 = rl(r5,47); \
    float fix = (lane==16)? q0 : (lane==32)? q1 : q2; \
    float pm0 = l16z ? ((lane==0)? INFV : fix) : yv; \
    float a0 = c0 + fminf(r0, pm0); \
    float a1 = c1 + fminf(r1, r0); \
    float a2 = c2 + fminf(r2, r1); \
    float a3 = c3 + fminf(r3, r2); \
    float a4 = c4 + fminf(r4, r3); \
    float a5 = c5 + fminf(r5, r4); \
    /* S = inclusive prefix sum of c across 384 */ \
    float s0=c0, s1=s0+c1, s2=s1+c2, s3=s2+c3, s4=s3+c4, s5=s4+c5; \
    float incl = scan_add16(s5); \
    float exl  = DPPF(incl, 0.0f, 0x111); \
    float t0 = rl(incl,15), t1 = rl(incl,31), t2 = rl(incl,47); \
    float rowoff = (row==0)? 0.0f : (row==1)? t0 : (row==2)? (t0+t1) : (t0+t1+t2); \
    float excl = exl + rowoff; \
    s0+=excl; s1+=excl; s2+=excl; s3+=excl; s4+=excl; s5+=excl; \
    /* prefix-min of (a - S); row = min(m, e) + S */ \
    float m0 = a0-s0; \
    float m1 = fminf(m0, a1-s1); \
    float m2 = fminf(m1, a2-s2); \
    float m3 = fminf(m2, a3-s3); \
    float m4 = fminf(m3, a4-s4); \
    float m5v = fminf(m4, a5-s5); \
    float im = scan_min16(m5v); \
    float ym = DPPF(im, INFV, 0x111); \
    float u0 = rl(im,15), u1 = rl(im,31), u2 = rl(im,47); \
    float moff = (row==0)? INFV : (row==1)? u0 : (row==2)? fminf(u0,u1) : fminf(u0,fminf(u1,u2)); \
    float e = fminf(ym, moff); \
    r0 = fminf(m0,e)+s0; \
    r1 = fminf(m1,e)+s1; \
    r2 = fminf(m2,e)+s2; \
    r3 = fminf(m3,e)+s3; \
    r4 = fminf(m4,e)+s4; \
    r5 = fminf(m5v,e)+s5; \
  } while(0)

  // row 0 loads first (oldest in vmcnt queue), then ring prologue
  uint32_t z0 = Cw[wb], z1 = Cw[wb+1], z2 = Cw[wb+2];

  uint32_t ra[8][3], rb[8][3];
#pragma unroll
  for (int u = 0; u < 8; u++) LOADR(ra, u, 1+u);
#pragma unroll
  for (int u = 0; u < 8; u++) LOADR(rb, u, 9+u);

  // ---- row 0: inclusive prefix sum of cost row 0 ----
  {
    float c0=bf2f(z0&0xffffu), c1=bf2f(z0>>16),
          c2=bf2f(z1&0xffffu), c3=bf2f(z1>>16),
          c4=bf2f(z2&0xffffu), c5=bf2f(z2>>16);
    float s0=c0, s1=s0+c1, s2=s1+c2, s3=s2+c3, s4=s3+c4, s5=s4+c5;
    float incl = scan_add16(s5);
    float exl  = DPPF(incl, 0.0f, 0x111);
    float t0 = rl(incl,15), t1 = rl(incl,31), t2 = rl(incl,47);
    float rowoff = (row==0)? 0.0f : (row==1)? t0 : (row==2)? (t0+t1) : (t0+t1+t2);
    float excl = exl + rowoff;
    r0=s0+excl; r1=s1+excl; r2=s2+excl; r3=s3+excl; r4=s4+excl; r5=s5+excl;
  }

  // ---- main: 23 outer iters x 16 rows = rows 1..368 ----
  int base = 1;
  for (int k = 0; k < 23; ++k, base += 16){
#pragma unroll
    for (int u = 0; u < 8; u++) ROW_BODY(ra[u][0], ra[u][1], ra[u][2]);
#pragma unroll
    for (int u = 0; u < 8; u++) LOADR(ra, u, base+16+u);
#pragma unroll
    for (int u = 0; u < 8; u++) ROW_BODY(rb[u][0], rb[u][1], rb[u][2]);
#pragma unroll
    for (int u = 0; u < 8; u++) LOADR(rb, u, base+24+u);
  }
  // ---- tail: ra holds rows 369..376, rb holds 377..383(+1 clamped dup) ----
#pragma unroll
  for (int u = 0; u < 8; u++) ROW_BODY(ra[u][0], ra[u][1], ra[u][2]);
#pragma unroll
  for (int u = 0; u < 7; u++) ROW_BODY(rb[u][0], rb[u][1], rb[u][2]);

  if (lane == 63) partial[b] = r5;
}

// ---------------------------------------------------------------------------
// Kernel 3: mean of 128 partials -> out[0]
// ---------------------------------------------------------------------------
__global__ __launch_bounds__(64) void dtw_reduce(
    const float* __restrict__ partial, float* __restrict__ out)
{
  const int l = threadIdx.x;
  float v = partial[l] + partial[l + 64];
#pragma unroll
  for (int d = 32; d >= 1; d >>= 1) v += __shfl_xor(v, d, 64);
  if (l == 0) out[0] = v * (1.0f/128.0f);
}

extern "C" void kernel_launch(void* const* d_in, const int* in_sizes, int n_in,
                              void* d_out, int out_size, void* d_ws, size_t ws_size,
                              hipStream_t stream)
{
  (void)in_sizes; (void)n_in; (void)out_size; (void)ws_size;
  const float* s1 = (const float*)d_in[0];
  const float* s2 = (const float*)d_in[1];
  float* out = (float*)d_out;

  ushort* cost    = (ushort*)d_ws;                                   // 128*384*384*2 B
  float*  partial = (float*)((char*)d_ws + (size_t)128*147456*2);    // 128 floats

  dtw_cost_gemm<<<dim3(9, 128), dim3(256), 0, stream>>>(s1, s2, cost);
  dtw_dp<<<dim3(128), dim3(64), 0, stream>>>(cost, partial);
  dtw_reduce<<<dim3(1), dim3(64), 0, stream>>>(partial, out);
}